// Round 10
// baseline (943.690 us; speedup 1.0000x reference)
//
#include <hip/hip_runtime.h>
#include <hip/hip_bf16.h>

#define NN 20000
#define EE 320000
#define LGN 4

typedef unsigned short u16;
typedef short bf16x8 __attribute__((ext_vector_type(8)));
typedef float f32x4 __attribute__((ext_vector_type(4)));

__device__ __forceinline__ float bf2f(u16 v) {
    unsigned int u = ((unsigned int)v) << 16;
    float f; __builtin_memcpy(&f, &u, 4); return f;
}
__device__ __forceinline__ u16 f2bf(float f) {
    __hip_bfloat16 h = __float2bfloat16(f);
    u16 u; __builtin_memcpy(&u, &h, 2); return u;
}

// async global->LDS, 16B per lane, LDS dest = wave-uniform base + lane*16
__device__ __forceinline__ void gll16(const void* g, void* l) {
    __builtin_amdgcn_global_load_lds(
        (const __attribute__((address_space(1))) unsigned int*)g,
        (__attribute__((address_space(3))) unsigned int*)l, 16, 0, 0);
}

// ---- pass 1: degree (by source), col histogram, ew copy-out ----
__global__ __launch_bounds__(256) void k_edge1(const int* __restrict__ ei,
                                               const float* __restrict__ ew,
                                               float* __restrict__ deg,
                                               int* __restrict__ counts,
                                               float* __restrict__ out_ew) {
    int e = blockIdx.x * 256 + threadIdx.x;
    if (e >= EE) return;
    int r = ei[e];
    float w = ew[e];
    atomicAdd(&deg[r], w);
    atomicAdd(&counts[ei[EE + e]], 1);
    out_ew[e] = w;
}

__global__ __launch_bounds__(256) void k_rsqrt(float* __restrict__ deg) {
    int i = blockIdx.x * 256 + threadIdx.x;
    if (i >= NN) return;
    float d = deg[i];
    deg[i] = (d > 0.f) ? rsqrtf(d) : 0.f;
}

// ---- exclusive scan of col histogram (single block) ----
__global__ __launch_bounds__(1024) void k_scan(const int* __restrict__ counts,
                                               int* __restrict__ offs) {
    __shared__ int part[1024];
    int t = threadIdx.x;
    const int C = (NN + 1023) / 1024;  // 20
    int lo = t * C, hi = min(lo + C, NN);
    int s = 0;
    for (int i = lo; i < hi; i++) s += counts[i];
    part[t] = s;
    __syncthreads();
    for (int off = 1; off < 1024; off <<= 1) {
        int add = (t >= off) ? part[t - off] : 0;
        __syncthreads();
        part[t] += add;
        __syncthreads();
    }
    int base = part[t] - s;
    for (int i = lo; i < hi; i++) { offs[i] = base; base += counts[i]; }
    if (t == 1023) offs[NN] = part[1023];
}

// ---- pass 2: compute norm, scatter (row, norm) int2 into CSR slots ----
__global__ __launch_bounds__(256) void k_scatter(const int* __restrict__ ei,
                                                 const float* __restrict__ ew,
                                                 const float* __restrict__ dis,
                                                 const int* __restrict__ offs,
                                                 int* __restrict__ cursor,
                                                 int2* __restrict__ nbrs) {
    int e = blockIdx.x * 256 + threadIdx.x;
    if (e >= EE) return;
    int r = ei[e], c = ei[EE + e];
    float nm = -(dis[r] * ew[e] * dis[c]);
    int pidx = offs[c] + atomicAdd(&cursor[c], 1);
    nbrs[pidx] = make_int2(r, __float_as_int(nm));
}

// ---- f32 -> bf16 cast (no transpose) ----
__global__ __launch_bounds__(256) void k_cast(const float* __restrict__ src,
                                              u16* __restrict__ dst, int n) {
    int i = blockIdx.x * 256 + threadIdx.x;
    if (i < n) dst[i] = f2bf(src[i]);
}

// ---- f32 [K][256] -> bf16 [256][K] transpose-cast (weights) ----
__global__ __launch_bounds__(256) void k_cast_T(const float* __restrict__ src,
                                                u16* __restrict__ dst, int K) {
    __shared__ u16 tile[32][33];
    int kt = blockIdx.x * 32, nt = blockIdx.y * 32;
    int tx = threadIdx.x & 31, ty = threadIdx.x >> 5;  // 32 x 8
#pragma unroll
    for (int i = 0; i < 32; i += 8)
        tile[ty + i][tx] = f2bf(src[(size_t)(kt + ty + i) * 256 + (nt + tx)]);
    __syncthreads();
#pragma unroll
    for (int i = 0; i < 32; i += 8)
        dst[(size_t)(nt + ty + i) * K + (kt + tx)] = tile[tx][ty + i];
}

// ---- fold BN affine: s = gamma*rsqrt(var+eps), t = beta - mean*s ----
__global__ __launch_bounds__(256) void k_foldbn(const float* __restrict__ g,
                                                const float* __restrict__ be,
                                                const float* __restrict__ mn,
                                                const float* __restrict__ vr,
                                                float* __restrict__ sc,
                                                float* __restrict__ sh) {
    int t = threadIdx.x;
    if (t < 256) {
        float s = g[t] * rsqrtf(vr[t] + 1e-5f);
        sc[t] = s;
        sh[t] = be[t] - mn[t] * s;
    }
}

// ---- CSR SpMM: one WAVE per node, paired-neighbor gathers (16 B/lane). ----
// Lanes 0-31 handle even neighbor of each pair, 32-63 the odd one; each half
// covers all 256 dims at 8 dims/lane; shfl_xor(32) combines the two halves.
__global__ __launch_bounds__(256) void k_prop(const u16* __restrict__ x, int ldx,
                                              const u16* __restrict__ xsub, int ldsub,
                                              int dotx2,
                                              u16* __restrict__ out, int ldo,
                                              const int* __restrict__ offs,
                                              const int2* __restrict__ nbrs) {
    int c = __builtin_amdgcn_readfirstlane(blockIdx.x * 4 + (threadIdx.x >> 6));
    int lane = threadIdx.x & 63;
    int h = lane >> 5, hl = lane & 31;
    int s = offs[c], e = offs[c + 1];
    float a[8] = {};
    for (int i = s; i < e; i += 8) {
        int2 mm[8];
#pragma unroll
        for (int j = 0; j < 8; j++) mm[j] = nbrs[i + j];
        u16 xv[4][8];
#pragma unroll
        for (int p = 0; p < 4; p++) {
            int r = mm[2 * p + h].x;
            uint4 t = *(const uint4*)(x + (size_t)r * ldx + hl * 8);
            __builtin_memcpy(xv[p], &t, 16);
        }
#pragma unroll
        for (int p = 0; p < 4; p++) {
            int idx = i + 2 * p + h;
            float w = (idx < e) ? __int_as_float(mm[2 * p + h].y) : 0.f;
#pragma unroll
            for (int d = 0; d < 8; d++) a[d] += w * bf2f(xv[p][d]);
        }
    }
#pragma unroll
    for (int d = 0; d < 8; d++) a[d] += __shfl_xor(a[d], 32, 64);
    if (dotx2) {
        u16 xs[8];
        uint4 t = *(const uint4*)(xsub + (size_t)c * ldsub + hl * 8);
        __builtin_memcpy(xs, &t, 16);
#pragma unroll
        for (int d = 0; d < 8; d++) a[d] = 2.f * a[d] - bf2f(xs[d]);
    }
    if (h == 0) {
        u16 o[8];
#pragma unroll
        for (int d = 0; d < 8; d++) o[d] = f2bf(a[d]);
        uint4 t;
        __builtin_memcpy(&t, o, 16);
        *(uint4*)(out + (size_t)c * ldo + hl * 8) = t;
    }
}

// ---- bf16 MFMA GEMM: SINGLE-WAVE blocks, 4-slot global_load_lds ring. ----
// Wave = 16 rows x 64 cols x full K; grid 5000 (strip = bid>>2, nq = bid&3).
// Per 32-k step: 5 DMA frags (4 B + 1 A, 5 KB) hardware-queued into LDS.
// 4-slot ring, staged 3 steps ahead; EXPLICIT s_waitcnt vmcnt(10) before the
// ds_reads (stage s was issued 3 iters earlier -> L2 latency covered; R9's NaN
// was the missing wait - compiler does NOT connect DMA LDS writes to ds_read).
// Slot-reuse safety: stage(s+3)'s slot was lgkm-drained before iter s-1's
// MFMAs, which precede the DMA issue in program order. Last 2 iters wait
// vmcnt(5)/vmcnt(0); loop exit leaves nothing outstanding -> epilogue reuse OK.
// mode 0: relu -> bf16 outb (ldob) via per-wave LDS transpose.
// mode 1: +bias, relu, BN affine, @w2 (+b2 on nq==0) -> atomicAdd f32 logits.
__global__ __launch_bounds__(64, 2) void k_gemm(
    const u16* __restrict__ A0, const u16* __restrict__ A1,
    const u16* __restrict__ A2, const u16* __restrict__ A3,
    int lda0, int lda1, int lda2, int lda3,
    int K, const u16* __restrict__ Bt,
    int mode,
    u16* __restrict__ outb, int ldob,
    const float* __restrict__ bias, const float* __restrict__ sc,
    const float* __restrict__ sh,
    const float* __restrict__ w2, const float* __restrict__ b2,
    float* __restrict__ outlog) {
    __shared__ __align__(16) u16 lds[4 * 5 * 512];  // 20 KB: 4 slots x 5 frags
    int l = threadIdx.x;
    int q = l >> 4, l16 = l & 15;
    int bid = blockIdx.x;
    int m0 = (bid >> 2) * 16;   // 0..19984, +l16 <= 19999: no guard
    int n0 = (bid & 3) * 64;
    const int steps = K >> 5;   // 24 or 32

    f32x4 acc[4] = {};

    auto stage = [&](int slot, int s) {
        int kt = s * 32;
        u16* base = lds + slot * 5 * 512;
        const u16* bg = Bt + (size_t)(n0 + l16) * K + kt + q * 8;
#pragma unroll
        for (int nt = 0; nt < 4; nt++) gll16(bg + (size_t)nt * 16 * K, base + nt * 512);
        int ch = kt >> 8;  // wave-uniform -> SGPR select
        const u16* ap;
        int la;
        if (ch == 0) { ap = A0; la = lda0; }
        else if (ch == 1) { ap = A1; la = lda1; }
        else if (ch == 2) { ap = A2; la = lda2; }
        else { ap = A3; la = lda3; }
        gll16(ap + (size_t)(m0 + l16) * la + (kt & 255) + q * 8, base + 4 * 512);
    };

    stage(0, 0);
    stage(1, 1);
    stage(2, 2);
    for (int s = 0; s < steps; s++) {
        // wait for stage s: 5 loads per stage, up to 2 newer stages in flight
        if (s + 3 <= steps) {
            asm volatile("s_waitcnt vmcnt(10)" ::: "memory");
        } else if (s + 2 <= steps) {
            asm volatile("s_waitcnt vmcnt(5)" ::: "memory");
        } else {
            asm volatile("s_waitcnt vmcnt(0)" ::: "memory");
        }
        const u16* base = lds + (s & 3) * 5 * 512;
        bf16x8 a = *(const bf16x8*)(base + 4 * 512 + l * 8);
        bf16x8 b[4];
#pragma unroll
        for (int nt = 0; nt < 4; nt++) b[nt] = *(const bf16x8*)(base + nt * 512 + l * 8);
        if (s + 3 < steps) stage((s + 3) & 3, s + 3);  // in flight across MFMAs
#pragma unroll
        for (int nt = 0; nt < 4; nt++)
            acc[nt] = __builtin_amdgcn_mfma_f32_16x16x32_bf16(a, b[nt], acc[nt], 0, 0, 0);
    }

    if (mode == 0) {
        u16* Cs = lds;  // [16][68]
#pragma unroll
        for (int nt = 0; nt < 4; nt++)
#pragma unroll
            for (int i = 0; i < 4; i++) {
                float v = acc[nt][i];
                v = v > 0.f ? v : 0.f;
                Cs[(q * 4 + i) * 68 + nt * 16 + l16] = f2bf(v);
            }
        // same-wave ds_write->ds_read ordered via lgkmcnt
        int r = l >> 2, cb = (l & 3) * 16;
#pragma unroll
        for (int j = 0; j < 2; j++) {
            uint4 cv = *(const uint4*)&Cs[r * 68 + cb + j * 8];
            *(uint4*)(outb + (size_t)(m0 + r) * ldob + n0 + cb + j * 8) = cv;
        }
    } else {
        float bi[4], s4[4], h4[4], wa[4], wb[4];
#pragma unroll
        for (int nt = 0; nt < 4; nt++) {
            int col = n0 + nt * 16 + l16;
            bi[nt] = bias[col];
            s4[nt] = sc[col];
            h4[nt] = sh[col];
            wa[nt] = w2[2 * col];
            wb[nt] = w2[2 * col + 1];
        }
        float b20 = b2[0], b21 = b2[1];
#pragma unroll
        for (int i = 0; i < 4; i++) {
            float p0 = 0.f, p1 = 0.f;
#pragma unroll
            for (int nt = 0; nt < 4; nt++) {
                float v = acc[nt][i] + bi[nt];
                v = v > 0.f ? v : 0.f;
                v = v * s4[nt] + h4[nt];
                p0 += v * wa[nt];
                p1 += v * wb[nt];
            }
#pragma unroll
            for (int off = 1; off < 16; off <<= 1) {
                p0 += __shfl_xor(p0, off, 64);
                p1 += __shfl_xor(p1, off, 64);
            }
            if (l16 == 0) {
                int row = m0 + q * 4 + i;
                float add0 = p0, add1 = p1;
                if ((bid & 3) == 0) { add0 += b20; add1 += b21; }
                atomicAdd(&outlog[row * 2 + 0], add0);
                atomicAdd(&outlog[row * 2 + 1], add1);
            }
        }
    }
}

extern "C" void kernel_launch(void* const* d_in, const int* in_sizes, int n_in,
                              void* d_out, int out_size, void* d_ws, size_t ws_size,
                              hipStream_t stream) {
    const float* features = (const float*)d_in[0];
    const int* ei = (const int*)d_in[1];
    // d_in[2] = edgenet_input (bypassed by edge_weight_override)
    const float* ew = (const float*)d_in[3];
    const float* cheb_w = (const float*)d_in[4];
    const float* w1 = (const float*)d_in[5];
    const float* b1 = (const float*)d_in[6];
    const float* g = (const float*)d_in[7];
    const float* be = (const float*)d_in[8];
    const float* mn = (const float*)d_in[9];
    const float* vr = (const float*)d_in[10];
    const float* w2 = (const float*)d_in[11];
    const float* b2 = (const float*)d_in[12];
    float* out = (float*)d_out;  // [NN*2] logits, then [EE] ew

    char* p = (char*)d_ws;
    auto alloc = [&](size_t bytes) -> char* {
        char* r = p;
        p += (bytes + 255) & ~(size_t)255;
        return r;
    };
    float* deg = (float*)alloc((size_t)NN * 4);
    int* counts = (int*)alloc((size_t)(NN + 1) * 4);
    int* cursor = (int*)alloc((size_t)NN * 4);
    size_t zero_bytes = (size_t)(p - (char*)deg);
    int* offs = (int*)alloc((size_t)(NN + 1) * 4);
    int2* nbrs = (int2*)alloc((size_t)(EE + 8) * 8);
    u16* xb = (u16*)alloc((size_t)NN * 256 * 2);
    u16* tx1 = (u16*)alloc((size_t)NN * 256 * 2);
    u16* tx2 = (u16*)alloc((size_t)NN * 256 * 2);
    u16* jk = (u16*)alloc((size_t)NN * 1024 * 2);
    u16* chebT = (u16*)alloc((size_t)LGN * 3 * 256 * 256 * 2);  // per layer [256][768]
    u16* w1T = (u16*)alloc((size_t)1024 * 256 * 2);             // [256][1024]
    float* sc = (float*)alloc(256 * 4);
    float* sh = (float*)alloc(256 * 4);

    hipMemsetAsync(deg, 0, zero_bytes, stream);
    hipMemsetAsync(nbrs + EE, 0, 8 * sizeof(int2), stream);  // safe overrun pad
    hipMemsetAsync(out, 0, (size_t)NN * 2 * 4, stream);      // logits accumulated atomically
    k_edge1<<<(EE + 255) / 256, 256, 0, stream>>>(ei, ew, deg, counts, out + (size_t)NN * 2);
    k_rsqrt<<<(NN + 255) / 256, 256, 0, stream>>>(deg);
    k_scan<<<1, 1024, 0, stream>>>(counts, offs);
    k_scatter<<<(EE + 255) / 256, 256, 0, stream>>>(ei, ew, deg, offs, cursor, nbrs);
    k_cast<<<((NN * 256) + 255) / 256, 256, 0, stream>>>(features, xb, NN * 256);
    for (int i = 0; i < LGN; i++)
        k_cast_T<<<dim3(24, 8), 256, 0, stream>>>(cheb_w + (size_t)i * 768 * 256,
                                                  chebT + (size_t)i * 256 * 768, 768);
    k_cast_T<<<dim3(32, 8), 256, 0, stream>>>(w1, w1T, 1024);
    k_foldbn<<<1, 256, 0, stream>>>(g, be, mn, vr, sc, sh);

    const int gg = (NN / 16) * 4;  // 5000 single-wave blocks
    for (int i = 0; i < LGN; i++) {
        const u16* x = (i == 0) ? xb : (jk + (size_t)(i - 1) * 256);
        int ldx = (i == 0) ? 256 : 1024;
        k_prop<<<NN / 4, 256, 0, stream>>>(x, ldx, (const u16*)nullptr, 0, 0, tx1, 256, offs,
                                           nbrs);
        k_prop<<<NN / 4, 256, 0, stream>>>(tx1, 256, x, ldx, 1, tx2, 256, offs, nbrs);
        k_gemm<<<gg, 64, 0, stream>>>(
            x, tx1, tx2, (const u16*)nullptr, ldx, 256, 256, 0, 768,
            chebT + (size_t)i * 256 * 768, 0, jk + (size_t)i * 256, 1024, (const float*)nullptr,
            (const float*)nullptr, (const float*)nullptr, (const float*)nullptr,
            (const float*)nullptr, (float*)nullptr);
    }
    k_gemm<<<gg, 64, 0, stream>>>(jk, jk + 256, jk + 512, jk + 768, 1024, 1024, 1024, 1024,
                                  1024, w1T, 1, (u16*)nullptr, 0, b1, sc, sh, w2, b2, out);
}

// Round 11
// 804.845 us; speedup vs baseline: 1.1725x; 1.1725x over previous
//
#include <hip/hip_runtime.h>
#include <hip/hip_bf16.h>

#define NN 20000
#define EE 320000
#define LGN 4

typedef unsigned short u16;
typedef short bf16x8 __attribute__((ext_vector_type(8)));
typedef float f32x4 __attribute__((ext_vector_type(4)));

__device__ __forceinline__ float bf2f(u16 v) {
    unsigned int u = ((unsigned int)v) << 16;
    float f; __builtin_memcpy(&f, &u, 4); return f;
}
__device__ __forceinline__ u16 f2bf(float f) {
    __hip_bfloat16 h = __float2bfloat16(f);
    u16 u; __builtin_memcpy(&u, &h, 2); return u;
}

// async global->LDS, 16B per lane, LDS dest = wave-uniform base + lane*16
__device__ __forceinline__ void gll16(const void* g, void* l) {
    __builtin_amdgcn_global_load_lds(
        (const __attribute__((address_space(1))) unsigned int*)g,
        (__attribute__((address_space(3))) unsigned int*)l, 16, 0, 0);
}

// ---- pass 1: degree (by source), col histogram, ew copy-out ----
__global__ __launch_bounds__(256) void k_edge1(const int* __restrict__ ei,
                                               const float* __restrict__ ew,
                                               float* __restrict__ deg,
                                               int* __restrict__ counts,
                                               float* __restrict__ out_ew) {
    int e = blockIdx.x * 256 + threadIdx.x;
    if (e >= EE) return;
    int r = ei[e];
    float w = ew[e];
    atomicAdd(&deg[r], w);
    atomicAdd(&counts[ei[EE + e]], 1);
    out_ew[e] = w;
}

__global__ __launch_bounds__(256) void k_rsqrt(float* __restrict__ deg) {
    int i = blockIdx.x * 256 + threadIdx.x;
    if (i >= NN) return;
    float d = deg[i];
    deg[i] = (d > 0.f) ? rsqrtf(d) : 0.f;
}

// ---- exclusive scan of col histogram (single block) ----
__global__ __launch_bounds__(1024) void k_scan(const int* __restrict__ counts,
                                               int* __restrict__ offs) {
    __shared__ int part[1024];
    int t = threadIdx.x;
    const int C = (NN + 1023) / 1024;  // 20
    int lo = t * C, hi = min(lo + C, NN);
    int s = 0;
    for (int i = lo; i < hi; i++) s += counts[i];
    part[t] = s;
    __syncthreads();
    for (int off = 1; off < 1024; off <<= 1) {
        int add = (t >= off) ? part[t - off] : 0;
        __syncthreads();
        part[t] += add;
        __syncthreads();
    }
    int base = part[t] - s;
    for (int i = lo; i < hi; i++) { offs[i] = base; base += counts[i]; }
    if (t == 1023) offs[NN] = part[1023];
}

// ---- pass 2: compute norm, scatter (row, norm) int2 into CSR slots ----
__global__ __launch_bounds__(256) void k_scatter(const int* __restrict__ ei,
                                                 const float* __restrict__ ew,
                                                 const float* __restrict__ dis,
                                                 const int* __restrict__ offs,
                                                 int* __restrict__ cursor,
                                                 int2* __restrict__ nbrs) {
    int e = blockIdx.x * 256 + threadIdx.x;
    if (e >= EE) return;
    int r = ei[e], c = ei[EE + e];
    float nm = -(dis[r] * ew[e] * dis[c]);
    int pidx = offs[c] + atomicAdd(&cursor[c], 1);
    nbrs[pidx] = make_int2(r, __float_as_int(nm));
}

// ---- f32 -> bf16 cast (no transpose) ----
__global__ __launch_bounds__(256) void k_cast(const float* __restrict__ src,
                                              u16* __restrict__ dst, int n) {
    int i = blockIdx.x * 256 + threadIdx.x;
    if (i < n) dst[i] = f2bf(src[i]);
}

// ---- f32 [K][256] -> bf16 [256][K] transpose-cast (weights) ----
__global__ __launch_bounds__(256) void k_cast_T(const float* __restrict__ src,
                                                u16* __restrict__ dst, int K) {
    __shared__ u16 tile[32][33];
    int kt = blockIdx.x * 32, nt = blockIdx.y * 32;
    int tx = threadIdx.x & 31, ty = threadIdx.x >> 5;  // 32 x 8
#pragma unroll
    for (int i = 0; i < 32; i += 8)
        tile[ty + i][tx] = f2bf(src[(size_t)(kt + ty + i) * 256 + (nt + tx)]);
    __syncthreads();
#pragma unroll
    for (int i = 0; i < 32; i += 8)
        dst[(size_t)(nt + ty + i) * K + (kt + tx)] = tile[tx][ty + i];
}

// ---- fold BN affine: s = gamma*rsqrt(var+eps), t = beta - mean*s ----
__global__ __launch_bounds__(256) void k_foldbn(const float* __restrict__ g,
                                                const float* __restrict__ be,
                                                const float* __restrict__ mn,
                                                const float* __restrict__ vr,
                                                float* __restrict__ sc,
                                                float* __restrict__ sh) {
    int t = threadIdx.x;
    if (t < 256) {
        float s = g[t] * rsqrtf(vr[t] + 1e-5f);
        sc[t] = s;
        sh[t] = be[t] - mn[t] * s;
    }
}

// ---- CSR SpMM: one WAVE per node, paired-neighbor gathers (16 B/lane). ----
__global__ __launch_bounds__(256) void k_prop(const u16* __restrict__ x, int ldx,
                                              const u16* __restrict__ xsub, int ldsub,
                                              int dotx2,
                                              u16* __restrict__ out, int ldo,
                                              const int* __restrict__ offs,
                                              const int2* __restrict__ nbrs) {
    int c = __builtin_amdgcn_readfirstlane(blockIdx.x * 4 + (threadIdx.x >> 6));
    int lane = threadIdx.x & 63;
    int h = lane >> 5, hl = lane & 31;
    int s = offs[c], e = offs[c + 1];
    float a[8] = {};
    for (int i = s; i < e; i += 8) {
        int2 mm[8];
#pragma unroll
        for (int j = 0; j < 8; j++) mm[j] = nbrs[i + j];
        u16 xv[4][8];
#pragma unroll
        for (int p = 0; p < 4; p++) {
            int r = mm[2 * p + h].x;
            uint4 t = *(const uint4*)(x + (size_t)r * ldx + hl * 8);
            __builtin_memcpy(xv[p], &t, 16);
        }
#pragma unroll
        for (int p = 0; p < 4; p++) {
            int idx = i + 2 * p + h;
            float w = (idx < e) ? __int_as_float(mm[2 * p + h].y) : 0.f;
#pragma unroll
            for (int d = 0; d < 8; d++) a[d] += w * bf2f(xv[p][d]);
        }
    }
#pragma unroll
    for (int d = 0; d < 8; d++) a[d] += __shfl_xor(a[d], 32, 64);
    if (dotx2) {
        u16 xs[8];
        uint4 t = *(const uint4*)(xsub + (size_t)c * ldsub + hl * 8);
        __builtin_memcpy(xs, &t, 16);
#pragma unroll
        for (int d = 0; d < 8; d++) a[d] = 2.f * a[d] - bf2f(xs[d]);
    }
    if (h == 0) {
        u16 o[8];
#pragma unroll
        for (int d = 0; d < 8; d++) o[d] = f2bf(a[d]);
        uint4 t;
        __builtin_memcpy(&t, o, 16);
        *(uint4*)(out + (size_t)c * ldo + hl * 8) = t;
    }
}

// ---- bf16 MFMA GEMM: R8 barrier-DMA structure, scaled. ----
// Block = 128 thr / 2 waves, tile M=32 x N=128, BK=64 -> grid 1250 blocks
// (4/CU by 40 KB LDS), 12 barrier steps (cheb) / 16 (classifier), 16 MFMA +
// 12 ds_read_b128 per wave per step. Frag layout per buf: B[nt*2+kq] (16),
// A[16 + mh*2+kq] (4); each frag 1 KB, DMA'd lane*16B = MFMA fragment order.
// Wave wv stages+reads B nt=wv*4..+3; A shared. b2 gated on first block+wave.
// mode 0: relu -> bf16 outb; mode 1: BN affine + @w2 -> atomicAdd f32 logits.
__global__ __launch_bounds__(128, 2) void k_gemm(
    const u16* __restrict__ A0, const u16* __restrict__ A1,
    const u16* __restrict__ A2, const u16* __restrict__ A3,
    int lda0, int lda1, int lda2, int lda3,
    int K, const u16* __restrict__ Bt,
    int mode,
    u16* __restrict__ outb, int ldob,
    const float* __restrict__ bias, const float* __restrict__ sc,
    const float* __restrict__ sh,
    const float* __restrict__ w2, const float* __restrict__ b2,
    float* __restrict__ outlog) {
    __shared__ __align__(16) u16 lds[2 * 20 * 512];  // 40 KB: 2 bufs x 20 frags
    int t = threadIdx.x;
    int wv = t >> 6, l = t & 63;
    int q = l >> 4, l16 = l & 15;
    int bid = blockIdx.x;
    int m0 = (bid >> 1) * 32;          // NN = 625*32 exact
    int n0 = (bid & 1) * 128 + wv * 64;  // this wave's 64-col window
    const int steps = K >> 6;  // 12 or 16

    f32x4 acc[2][4] = {};

    auto stage = [&](int buf, int s) {
        int kt = s * 64;
        u16* base = lds + buf * 20 * 512;
        // B: this wave's 4 n-tiles x 2 k-halves
#pragma unroll
        for (int j = 0; j < 4; j++) {
            const u16* bg = Bt + (size_t)(n0 + j * 16 + l16) * K + kt + q * 8;
#pragma unroll
            for (int kq = 0; kq < 2; kq++)
                gll16(bg + kq * 32, base + ((wv * 4 + j) * 2 + kq) * 512);
        }
        // A: wave wv stages m-half wv (both k-halves); kt&255 never crosses 256
        int ch = kt >> 8;  // wave-uniform -> SGPR select
        const u16* ap;
        int la;
        if (ch == 0) { ap = A0; la = lda0; }
        else if (ch == 1) { ap = A1; la = lda1; }
        else if (ch == 2) { ap = A2; la = lda2; }
        else { ap = A3; la = lda3; }
        const u16* ag = ap + (size_t)(m0 + wv * 16 + l16) * la + (kt & 255) + q * 8;
#pragma unroll
        for (int kq = 0; kq < 2; kq++)
            gll16(ag + kq * 32, base + (16 + wv * 2 + kq) * 512);
    };

    stage(0, 0);
    for (int s = 0; s < steps; s++) {
        __syncthreads();  // drains stage(s) DMAs (vmcnt(0)) + prev reads
        if (s + 1 < steps) stage((s + 1) & 1, s + 1);
        const u16* base = lds + (s & 1) * 20 * 512;
#pragma unroll
        for (int kq = 0; kq < 2; kq++) {
            bf16x8 a[2], b[4];
#pragma unroll
            for (int mh = 0; mh < 2; mh++)
                a[mh] = *(const bf16x8*)(base + (16 + mh * 2 + kq) * 512 + l * 8);
#pragma unroll
            for (int j = 0; j < 4; j++)
                b[j] = *(const bf16x8*)(base + ((wv * 4 + j) * 2 + kq) * 512 + l * 8);
#pragma unroll
            for (int mh = 0; mh < 2; mh++)
#pragma unroll
                for (int j = 0; j < 4; j++)
                    acc[mh][j] =
                        __builtin_amdgcn_mfma_f32_16x16x32_bf16(a[mh], b[j], acc[mh][j], 0, 0, 0);
        }
    }
    // loop ended with final buf = (steps-1)&1 = 1 (steps even); epilogue reuses
    // buf 0's region per wave -> no cross-wave race with last reads.

    if (mode == 0) {
        u16* Cs = lds + wv * 2304;  // per-wave [32][72]
#pragma unroll
        for (int mh = 0; mh < 2; mh++)
#pragma unroll
            for (int j = 0; j < 4; j++)
#pragma unroll
                for (int i = 0; i < 4; i++) {
                    float v = acc[mh][j][i];
                    v = v > 0.f ? v : 0.f;
                    Cs[(mh * 16 + q * 4 + i) * 72 + j * 16 + l16] = f2bf(v);
                }
        // same-wave ds_write->ds_read ordered via lgkmcnt
        int r = l >> 1, cb = (l & 1) * 32;
#pragma unroll
        for (int j = 0; j < 4; j++) {
            uint4 cv = *(const uint4*)&Cs[r * 72 + cb + j * 8];
            *(uint4*)(outb + (size_t)(m0 + r) * ldob + n0 + cb + j * 8) = cv;
        }
    } else {
        float bi[4], s4[4], h4[4], wa[4], wb[4];
#pragma unroll
        for (int j = 0; j < 4; j++) {
            int col = n0 + j * 16 + l16;
            bi[j] = bias[col];
            s4[j] = sc[col];
            h4[j] = sh[col];
            wa[j] = w2[2 * col];
            wb[j] = w2[2 * col + 1];
        }
        float b20 = b2[0], b21 = b2[1];
        bool addb = ((bid & 1) == 0) && (wv == 0);
#pragma unroll
        for (int mh = 0; mh < 2; mh++)
#pragma unroll
            for (int i = 0; i < 4; i++) {
                float p0 = 0.f, p1 = 0.f;
#pragma unroll
                for (int j = 0; j < 4; j++) {
                    float v = acc[mh][j][i] + bi[j];
                    v = v > 0.f ? v : 0.f;
                    v = v * s4[j] + h4[j];
                    p0 += v * wa[j];
                    p1 += v * wb[j];
                }
#pragma unroll
                for (int off = 1; off < 16; off <<= 1) {
                    p0 += __shfl_xor(p0, off, 64);
                    p1 += __shfl_xor(p1, off, 64);
                }
                if (l16 == 0) {
                    int row = m0 + mh * 16 + q * 4 + i;
                    float add0 = p0, add1 = p1;
                    if (addb) { add0 += b20; add1 += b21; }
                    atomicAdd(&outlog[row * 2 + 0], add0);
                    atomicAdd(&outlog[row * 2 + 1], add1);
                }
            }
    }
}

extern "C" void kernel_launch(void* const* d_in, const int* in_sizes, int n_in,
                              void* d_out, int out_size, void* d_ws, size_t ws_size,
                              hipStream_t stream) {
    const float* features = (const float*)d_in[0];
    const int* ei = (const int*)d_in[1];
    // d_in[2] = edgenet_input (bypassed by edge_weight_override)
    const float* ew = (const float*)d_in[3];
    const float* cheb_w = (const float*)d_in[4];
    const float* w1 = (const float*)d_in[5];
    const float* b1 = (const float*)d_in[6];
    const float* g = (const float*)d_in[7];
    const float* be = (const float*)d_in[8];
    const float* mn = (const float*)d_in[9];
    const float* vr = (const float*)d_in[10];
    const float* w2 = (const float*)d_in[11];
    const float* b2 = (const float*)d_in[12];
    float* out = (float*)d_out;  // [NN*2] logits, then [EE] ew

    char* p = (char*)d_ws;
    auto alloc = [&](size_t bytes) -> char* {
        char* r = p;
        p += (bytes + 255) & ~(size_t)255;
        return r;
    };
    float* deg = (float*)alloc((size_t)NN * 4);
    int* counts = (int*)alloc((size_t)(NN + 1) * 4);
    int* cursor = (int*)alloc((size_t)NN * 4);
    size_t zero_bytes = (size_t)(p - (char*)deg);
    int* offs = (int*)alloc((size_t)(NN + 1) * 4);
    int2* nbrs = (int2*)alloc((size_t)(EE + 8) * 8);
    u16* xb = (u16*)alloc((size_t)NN * 256 * 2);
    u16* tx1 = (u16*)alloc((size_t)NN * 256 * 2);
    u16* tx2 = (u16*)alloc((size_t)NN * 256 * 2);
    u16* jk = (u16*)alloc((size_t)NN * 1024 * 2);
    u16* chebT = (u16*)alloc((size_t)LGN * 3 * 256 * 256 * 2);  // per layer [256][768]
    u16* w1T = (u16*)alloc((size_t)1024 * 256 * 2);             // [256][1024]
    float* sc = (float*)alloc(256 * 4);
    float* sh = (float*)alloc(256 * 4);

    hipMemsetAsync(deg, 0, zero_bytes, stream);
    hipMemsetAsync(nbrs + EE, 0, 8 * sizeof(int2), stream);  // safe overrun pad
    hipMemsetAsync(out, 0, (size_t)NN * 2 * 4, stream);      // logits accumulated atomically
    k_edge1<<<(EE + 255) / 256, 256, 0, stream>>>(ei, ew, deg, counts, out + (size_t)NN * 2);
    k_rsqrt<<<(NN + 255) / 256, 256, 0, stream>>>(deg);
    k_scan<<<1, 1024, 0, stream>>>(counts, offs);
    k_scatter<<<(EE + 255) / 256, 256, 0, stream>>>(ei, ew, deg, offs, cursor, nbrs);
    k_cast<<<((NN * 256) + 255) / 256, 256, 0, stream>>>(features, xb, NN * 256);
    for (int i = 0; i < LGN; i++)
        k_cast_T<<<dim3(24, 8), 256, 0, stream>>>(cheb_w + (size_t)i * 768 * 256,
                                                  chebT + (size_t)i * 256 * 768, 768);
    k_cast_T<<<dim3(32, 8), 256, 0, stream>>>(w1, w1T, 1024);
    k_foldbn<<<1, 256, 0, stream>>>(g, be, mn, vr, sc, sh);

    const int gg = (NN / 32) * 2;  // 1250 blocks (625 strips x 2 n-halves)
    for (int i = 0; i < LGN; i++) {
        const u16* x = (i == 0) ? xb : (jk + (size_t)(i - 1) * 256);
        int ldx = (i == 0) ? 256 : 1024;
        k_prop<<<NN / 4, 256, 0, stream>>>(x, ldx, (const u16*)nullptr, 0, 0, tx1, 256, offs,
                                           nbrs);
        k_prop<<<NN / 4, 256, 0, stream>>>(tx1, 256, x, ldx, 1, tx2, 256, offs, nbrs);
        k_gemm<<<gg, 128, 0, stream>>>(
            x, tx1, tx2, (const u16*)nullptr, ldx, 256, 256, 0, 768,
            chebT + (size_t)i * 256 * 768, 0, jk + (size_t)i * 256, 1024, (const float*)nullptr,
            (const float*)nullptr, (const float*)nullptr, (const float*)nullptr,
            (const float*)nullptr, (float*)nullptr);
    }
    k_gemm<<<gg, 128, 0, stream>>>(jk, jk + 256, jk + 512, jk + 768, 1024, 1024, 1024, 1024,
                                   1024, w1T, 1, (u16*)nullptr, 0, b1, sc, sh, w2, b2, out);
}

// Round 12
// 595.373 us; speedup vs baseline: 1.5850x; 1.3518x over previous
//
#include <hip/hip_runtime.h>
#include <hip/hip_bf16.h>

#define NN 20000
#define EE 320000
#define LGN 4

typedef unsigned short u16;
typedef short bf16x8 __attribute__((ext_vector_type(8)));
typedef float f32x4 __attribute__((ext_vector_type(4)));

__device__ __forceinline__ float bf2f(u16 v) {
    unsigned int u = ((unsigned int)v) << 16;
    float f; __builtin_memcpy(&f, &u, 4); return f;
}
__device__ __forceinline__ u16 f2bf(float f) {
    __hip_bfloat16 h = __float2bfloat16(f);
    u16 u; __builtin_memcpy(&u, &h, 2); return u;
}

// async global->LDS, 16B per lane, LDS dest = wave-uniform base + lane*16
__device__ __forceinline__ void gll16(const void* g, void* l) {
    __builtin_amdgcn_global_load_lds(
        (const __attribute__((address_space(1))) unsigned int*)g,
        (__attribute__((address_space(3))) unsigned int*)l, 16, 0, 0);
}

// ---- pass 1: degree (by source), col histogram, ew copy-out ----
__global__ __launch_bounds__(256) void k_edge1(const int* __restrict__ ei,
                                               const float* __restrict__ ew,
                                               float* __restrict__ deg,
                                               int* __restrict__ counts,
                                               float* __restrict__ out_ew) {
    int e = blockIdx.x * 256 + threadIdx.x;
    if (e >= EE) return;
    int r = ei[e];
    float w = ew[e];
    atomicAdd(&deg[r], w);
    atomicAdd(&counts[ei[EE + e]], 1);
    out_ew[e] = w;
}

__global__ __launch_bounds__(256) void k_rsqrt(float* __restrict__ deg) {
    int i = blockIdx.x * 256 + threadIdx.x;
    if (i >= NN) return;
    float d = deg[i];
    deg[i] = (d > 0.f) ? rsqrtf(d) : 0.f;
}

// ---- exclusive scan of col histogram (single block) ----
__global__ __launch_bounds__(1024) void k_scan(const int* __restrict__ counts,
                                               int* __restrict__ offs) {
    __shared__ int part[1024];
    int t = threadIdx.x;
    const int C = (NN + 1023) / 1024;  // 20
    int lo = t * C, hi = min(lo + C, NN);
    int s = 0;
    for (int i = lo; i < hi; i++) s += counts[i];
    part[t] = s;
    __syncthreads();
    for (int off = 1; off < 1024; off <<= 1) {
        int add = (t >= off) ? part[t - off] : 0;
        __syncthreads();
        part[t] += add;
        __syncthreads();
    }
    int base = part[t] - s;
    for (int i = lo; i < hi; i++) { offs[i] = base; base += counts[i]; }
    if (t == 1023) offs[NN] = part[1023];
}

// ---- pass 2: compute norm, scatter (row, norm) int2 into CSR slots ----
__global__ __launch_bounds__(256) void k_scatter(const int* __restrict__ ei,
                                                 const float* __restrict__ ew,
                                                 const float* __restrict__ dis,
                                                 const int* __restrict__ offs,
                                                 int* __restrict__ cursor,
                                                 int2* __restrict__ nbrs) {
    int e = blockIdx.x * 256 + threadIdx.x;
    if (e >= EE) return;
    int r = ei[e], c = ei[EE + e];
    float nm = -(dis[r] * ew[e] * dis[c]);
    int pidx = offs[c] + atomicAdd(&cursor[c], 1);
    nbrs[pidx] = make_int2(r, __float_as_int(nm));
}

// ---- f32 -> bf16 cast (no transpose) ----
__global__ __launch_bounds__(256) void k_cast(const float* __restrict__ src,
                                              u16* __restrict__ dst, int n) {
    int i = blockIdx.x * 256 + threadIdx.x;
    if (i < n) dst[i] = f2bf(src[i]);
}

// ---- f32 [K][256] -> bf16 [256][K] transpose-cast (weights) ----
__global__ __launch_bounds__(256) void k_cast_T(const float* __restrict__ src,
                                                u16* __restrict__ dst, int K) {
    __shared__ u16 tile[32][33];
    int kt = blockIdx.x * 32, nt = blockIdx.y * 32;
    int tx = threadIdx.x & 31, ty = threadIdx.x >> 5;  // 32 x 8
#pragma unroll
    for (int i = 0; i < 32; i += 8)
        tile[ty + i][tx] = f2bf(src[(size_t)(kt + ty + i) * 256 + (nt + tx)]);
    __syncthreads();
#pragma unroll
    for (int i = 0; i < 32; i += 8)
        dst[(size_t)(nt + ty + i) * K + (kt + tx)] = tile[tx][ty + i];
}

// ---- fold BN affine: s = gamma*rsqrt(var+eps), t = beta - mean*s ----
__global__ __launch_bounds__(256) void k_foldbn(const float* __restrict__ g,
                                                const float* __restrict__ be,
                                                const float* __restrict__ mn,
                                                const float* __restrict__ vr,
                                                float* __restrict__ sc,
                                                float* __restrict__ sh) {
    int t = threadIdx.x;
    if (t < 256) {
        float s = g[t] * rsqrtf(vr[t] + 1e-5f);
        sc[t] = s;
        sh[t] = be[t] - mn[t] * s;
    }
}

// ---- CSR SpMM: one WAVE per node, no LDS, no barriers, 8 gathers in flight ----
// R8-proven form: each gather instruction reads ONE row (64 lanes x 8 B =
// 512 B); 8 independent loads in flight per wave (MLP is what hides latency -
// R9's paired 4x16B variant halved issue depth and ran 2x slower).
__global__ __launch_bounds__(256) void k_prop(const u16* __restrict__ x, int ldx,
                                              const u16* __restrict__ xsub, int ldsub,
                                              int dotx2,
                                              u16* __restrict__ out, int ldo,
                                              const int* __restrict__ offs,
                                              const int2* __restrict__ nbrs) {
    int c = __builtin_amdgcn_readfirstlane(blockIdx.x * 4 + (threadIdx.x >> 6));
    int lane = threadIdx.x & 63;
    int s = offs[c], e = offs[c + 1];
    float a0 = 0.f, a1 = 0.f, a2 = 0.f, a3 = 0.f;
    for (int i = s; i < e; i += 8) {
        int2 mm[8];
        ushort4 xv[8];
#pragma unroll
        for (int j = 0; j < 8; j++) mm[j] = nbrs[i + j];
#pragma unroll
        for (int j = 0; j < 8; j++)
            xv[j] = *(const ushort4*)(x + (size_t)mm[j].x * ldx + lane * 4);
#pragma unroll
        for (int j = 0; j < 8; j++) {
            float w = (i + j < e) ? __int_as_float(mm[j].y) : 0.f;
            a0 += w * bf2f(xv[j].x);
            a1 += w * bf2f(xv[j].y);
            a2 += w * bf2f(xv[j].z);
            a3 += w * bf2f(xv[j].w);
        }
    }
    if (dotx2) {
        ushort4 xs = *(const ushort4*)(xsub + (size_t)c * ldsub + lane * 4);
        a0 = 2.f * a0 - bf2f(xs.x);
        a1 = 2.f * a1 - bf2f(xs.y);
        a2 = 2.f * a2 - bf2f(xs.z);
        a3 = 2.f * a3 - bf2f(xs.w);
    }
    ushort4 o;
    o.x = f2bf(a0); o.y = f2bf(a1); o.z = f2bf(a2); o.w = f2bf(a3);
    *(ushort4*)(out + (size_t)c * ldo + lane * 4) = o;
}

// ---- bf16 MFMA GEMM: R8 barrier-DMA structure, scaled (R11, unchanged). ----
// Block = 128 thr / 2 waves, tile M=32 x N=128, BK=64 -> grid 1250 blocks
// (4/CU by 40 KB LDS), 12/16 barrier steps, 16 MFMA + 12 ds_read_b128 per
// wave per step. DMA'd lane*16B = MFMA fragment order.
// mode 0: relu -> bf16 outb; mode 1: BN affine + @w2 -> atomicAdd f32 logits.
__global__ __launch_bounds__(128, 2) void k_gemm(
    const u16* __restrict__ A0, const u16* __restrict__ A1,
    const u16* __restrict__ A2, const u16* __restrict__ A3,
    int lda0, int lda1, int lda2, int lda3,
    int K, const u16* __restrict__ Bt,
    int mode,
    u16* __restrict__ outb, int ldob,
    const float* __restrict__ bias, const float* __restrict__ sc,
    const float* __restrict__ sh,
    const float* __restrict__ w2, const float* __restrict__ b2,
    float* __restrict__ outlog) {
    __shared__ __align__(16) u16 lds[2 * 20 * 512];  // 40 KB: 2 bufs x 20 frags
    int t = threadIdx.x;
    int wv = t >> 6, l = t & 63;
    int q = l >> 4, l16 = l & 15;
    int bid = blockIdx.x;
    int m0 = (bid >> 1) * 32;          // NN = 625*32 exact
    int n0 = (bid & 1) * 128 + wv * 64;  // this wave's 64-col window
    const int steps = K >> 6;  // 12 or 16

    f32x4 acc[2][4] = {};

    auto stage = [&](int buf, int s) {
        int kt = s * 64;
        u16* base = lds + buf * 20 * 512;
#pragma unroll
        for (int j = 0; j < 4; j++) {
            const u16* bg = Bt + (size_t)(n0 + j * 16 + l16) * K + kt + q * 8;
#pragma unroll
            for (int kq = 0; kq < 2; kq++)
                gll16(bg + kq * 32, base + ((wv * 4 + j) * 2 + kq) * 512);
        }
        int ch = kt >> 8;  // wave-uniform -> SGPR select
        const u16* ap;
        int la;
        if (ch == 0) { ap = A0; la = lda0; }
        else if (ch == 1) { ap = A1; la = lda1; }
        else if (ch == 2) { ap = A2; la = lda2; }
        else { ap = A3; la = lda3; }
        const u16* ag = ap + (size_t)(m0 + wv * 16 + l16) * la + (kt & 255) + q * 8;
#pragma unroll
        for (int kq = 0; kq < 2; kq++)
            gll16(ag + kq * 32, base + (16 + wv * 2 + kq) * 512);
    };

    stage(0, 0);
    for (int s = 0; s < steps; s++) {
        __syncthreads();  // drains stage(s) DMAs (vmcnt(0)) + prev reads
        if (s + 1 < steps) stage((s + 1) & 1, s + 1);
        const u16* base = lds + (s & 1) * 20 * 512;
#pragma unroll
        for (int kq = 0; kq < 2; kq++) {
            bf16x8 a[2], b[4];
#pragma unroll
            for (int mh = 0; mh < 2; mh++)
                a[mh] = *(const bf16x8*)(base + (16 + mh * 2 + kq) * 512 + l * 8);
#pragma unroll
            for (int j = 0; j < 4; j++)
                b[j] = *(const bf16x8*)(base + ((wv * 4 + j) * 2 + kq) * 512 + l * 8);
#pragma unroll
            for (int mh = 0; mh < 2; mh++)
#pragma unroll
                for (int j = 0; j < 4; j++)
                    acc[mh][j] =
                        __builtin_amdgcn_mfma_f32_16x16x32_bf16(a[mh], b[j], acc[mh][j], 0, 0, 0);
        }
    }

    if (mode == 0) {
        u16* Cs = lds + wv * 2304;  // per-wave [32][72]
#pragma unroll
        for (int mh = 0; mh < 2; mh++)
#pragma unroll
            for (int j = 0; j < 4; j++)
#pragma unroll
                for (int i = 0; i < 4; i++) {
                    float v = acc[mh][j][i];
                    v = v > 0.f ? v : 0.f;
                    Cs[(mh * 16 + q * 4 + i) * 72 + j * 16 + l16] = f2bf(v);
                }
        // same-wave ds_write->ds_read ordered via lgkmcnt
        int r = l >> 1, cb = (l & 1) * 32;
#pragma unroll
        for (int j = 0; j < 4; j++) {
            uint4 cv = *(const uint4*)&Cs[r * 72 + cb + j * 8];
            *(uint4*)(outb + (size_t)(m0 + r) * ldob + n0 + cb + j * 8) = cv;
        }
    } else {
        float bi[4], s4[4], h4[4], wa[4], wb[4];
#pragma unroll
        for (int j = 0; j < 4; j++) {
            int col = n0 + j * 16 + l16;
            bi[j] = bias[col];
            s4[j] = sc[col];
            h4[j] = sh[col];
            wa[j] = w2[2 * col];
            wb[j] = w2[2 * col + 1];
        }
        float b20 = b2[0], b21 = b2[1];
        bool addb = ((bid & 1) == 0) && (wv == 0);
#pragma unroll
        for (int mh = 0; mh < 2; mh++)
#pragma unroll
            for (int i = 0; i < 4; i++) {
                float p0 = 0.f, p1 = 0.f;
#pragma unroll
                for (int j = 0; j < 4; j++) {
                    float v = acc[mh][j][i] + bi[j];
                    v = v > 0.f ? v : 0.f;
                    v = v * s4[j] + h4[j];
                    p0 += v * wa[j];
                    p1 += v * wb[j];
                }
#pragma unroll
                for (int off = 1; off < 16; off <<= 1) {
                    p0 += __shfl_xor(p0, off, 64);
                    p1 += __shfl_xor(p1, off, 64);
                }
                if (l16 == 0) {
                    int row = m0 + mh * 16 + q * 4 + i;
                    float add0 = p0, add1 = p1;
                    if (addb) { add0 += b20; add1 += b21; }
                    atomicAdd(&outlog[row * 2 + 0], add0);
                    atomicAdd(&outlog[row * 2 + 1], add1);
                }
            }
    }
}

extern "C" void kernel_launch(void* const* d_in, const int* in_sizes, int n_in,
                              void* d_out, int out_size, void* d_ws, size_t ws_size,
                              hipStream_t stream) {
    const float* features = (const float*)d_in[0];
    const int* ei = (const int*)d_in[1];
    // d_in[2] = edgenet_input (bypassed by edge_weight_override)
    const float* ew = (const float*)d_in[3];
    const float* cheb_w = (const float*)d_in[4];
    const float* w1 = (const float*)d_in[5];
    const float* b1 = (const float*)d_in[6];
    const float* g = (const float*)d_in[7];
    const float* be = (const float*)d_in[8];
    const float* mn = (const float*)d_in[9];
    const float* vr = (const float*)d_in[10];
    const float* w2 = (const float*)d_in[11];
    const float* b2 = (const float*)d_in[12];
    float* out = (float*)d_out;  // [NN*2] logits, then [EE] ew

    char* p = (char*)d_ws;
    auto alloc = [&](size_t bytes) -> char* {
        char* r = p;
        p += (bytes + 255) & ~(size_t)255;
        return r;
    };
    float* deg = (float*)alloc((size_t)NN * 4);
    int* counts = (int*)alloc((size_t)(NN + 1) * 4);
    int* cursor = (int*)alloc((size_t)NN * 4);
    size_t zero_bytes = (size_t)(p - (char*)deg);
    int* offs = (int*)alloc((size_t)(NN + 1) * 4);
    int2* nbrs = (int2*)alloc((size_t)(EE + 8) * 8);
    u16* xb = (u16*)alloc((size_t)NN * 256 * 2);
    u16* tx1 = (u16*)alloc((size_t)NN * 256 * 2);
    u16* tx2 = (u16*)alloc((size_t)NN * 256 * 2);
    u16* jk = (u16*)alloc((size_t)NN * 1024 * 2);
    u16* chebT = (u16*)alloc((size_t)LGN * 3 * 256 * 256 * 2);  // per layer [256][768]
    u16* w1T = (u16*)alloc((size_t)1024 * 256 * 2);             // [256][1024]
    float* sc = (float*)alloc(256 * 4);
    float* sh = (float*)alloc(256 * 4);

    hipMemsetAsync(deg, 0, zero_bytes, stream);
    hipMemsetAsync(nbrs + EE, 0, 8 * sizeof(int2), stream);  // safe overrun pad
    hipMemsetAsync(out, 0, (size_t)NN * 2 * 4, stream);      // logits accumulated atomically
    k_edge1<<<(EE + 255) / 256, 256, 0, stream>>>(ei, ew, deg, counts, out + (size_t)NN * 2);
    k_rsqrt<<<(NN + 255) / 256, 256, 0, stream>>>(deg);
    k_scan<<<1, 1024, 0, stream>>>(counts, offs);
    k_scatter<<<(EE + 255) / 256, 256, 0, stream>>>(ei, ew, deg, offs, cursor, nbrs);
    k_cast<<<((NN * 256) + 255) / 256, 256, 0, stream>>>(features, xb, NN * 256);
    for (int i = 0; i < LGN; i++)
        k_cast_T<<<dim3(24, 8), 256, 0, stream>>>(cheb_w + (size_t)i * 768 * 256,
                                                  chebT + (size_t)i * 256 * 768, 768);
    k_cast_T<<<dim3(32, 8), 256, 0, stream>>>(w1, w1T, 1024);
    k_foldbn<<<1, 256, 0, stream>>>(g, be, mn, vr, sc, sh);

    const int gg = (NN / 32) * 2;  // 1250 blocks (625 strips x 2 n-halves)
    for (int i = 0; i < LGN; i++) {
        const u16* x = (i == 0) ? xb : (jk + (size_t)(i - 1) * 256);
        int ldx = (i == 0) ? 256 : 1024;
        k_prop<<<NN / 4, 256, 0, stream>>>(x, ldx, (const u16*)nullptr, 0, 0, tx1, 256, offs,
                                           nbrs);
        k_prop<<<NN / 4, 256, 0, stream>>>(tx1, 256, x, ldx, 1, tx2, 256, offs, nbrs);
        k_gemm<<<gg, 128, 0, stream>>>(
            x, tx1, tx2, (const u16*)nullptr, ldx, 256, 256, 0, 768,
            chebT + (size_t)i * 256 * 768, 0, jk + (size_t)i * 256, 1024, (const float*)nullptr,
            (const float*)nullptr, (const float*)nullptr, (const float*)nullptr,
            (const float*)nullptr, (float*)nullptr);
    }
    k_gemm<<<gg, 128, 0, stream>>>(jk, jk + 256, jk + 512, jk + 768, 1024, 1024, 1024, 1024,
                                   1024, w1T, 1, (u16*)nullptr, 0, b1, sc, sh, w2, b2, out);
}

// Round 13
// 523.978 us; speedup vs baseline: 1.8010x; 1.1363x over previous
//
#include <hip/hip_runtime.h>
#include <hip/hip_bf16.h>

#define NN 20000
#define EE 320000
#define LGN 4

typedef unsigned short u16;
typedef short bf16x8 __attribute__((ext_vector_type(8)));
typedef float f32x4 __attribute__((ext_vector_type(4)));

__device__ __forceinline__ float bf2f(u16 v) {
    unsigned int u = ((unsigned int)v) << 16;
    float f; __builtin_memcpy(&f, &u, 4); return f;
}
__device__ __forceinline__ u16 f2bf(float f) {
    __hip_bfloat16 h = __float2bfloat16(f);
    u16 u; __builtin_memcpy(&u, &h, 2); return u;
}

// async global->LDS, 16B per lane, LDS dest = wave-uniform base + lane*16
__device__ __forceinline__ void gll16(const void* g, void* l) {
    __builtin_amdgcn_global_load_lds(
        (const __attribute__((address_space(1))) unsigned int*)g,
        (__attribute__((address_space(3))) unsigned int*)l, 16, 0, 0);
}

// ---- pass 1: degree (by source), col histogram, ew copy-out ----
__global__ __launch_bounds__(256) void k_edge1(const int* __restrict__ ei,
                                               const float* __restrict__ ew,
                                               float* __restrict__ deg,
                                               int* __restrict__ counts,
                                               float* __restrict__ out_ew) {
    int e = blockIdx.x * 256 + threadIdx.x;
    if (e >= EE) return;
    int r = ei[e];
    float w = ew[e];
    atomicAdd(&deg[r], w);
    atomicAdd(&counts[ei[EE + e]], 1);
    out_ew[e] = w;
}

__global__ __launch_bounds__(256) void k_rsqrt(float* __restrict__ deg) {
    int i = blockIdx.x * 256 + threadIdx.x;
    if (i >= NN) return;
    float d = deg[i];
    deg[i] = (d > 0.f) ? rsqrtf(d) : 0.f;
}

// ---- exclusive scan of col histogram (single block) ----
__global__ __launch_bounds__(1024) void k_scan(const int* __restrict__ counts,
                                               int* __restrict__ offs) {
    __shared__ int part[1024];
    int t = threadIdx.x;
    const int C = (NN + 1023) / 1024;  // 20
    int lo = t * C, hi = min(lo + C, NN);
    int s = 0;
    for (int i = lo; i < hi; i++) s += counts[i];
    part[t] = s;
    __syncthreads();
    for (int off = 1; off < 1024; off <<= 1) {
        int add = (t >= off) ? part[t - off] : 0;
        __syncthreads();
        part[t] += add;
        __syncthreads();
    }
    int base = part[t] - s;
    for (int i = lo; i < hi; i++) { offs[i] = base; base += counts[i]; }
    if (t == 1023) offs[NN] = part[1023];
}

// ---- pass 2: compute norm, scatter (row, norm) int2 into CSR slots ----
__global__ __launch_bounds__(256) void k_scatter(const int* __restrict__ ei,
                                                 const float* __restrict__ ew,
                                                 const float* __restrict__ dis,
                                                 const int* __restrict__ offs,
                                                 int* __restrict__ cursor,
                                                 int2* __restrict__ nbrs) {
    int e = blockIdx.x * 256 + threadIdx.x;
    if (e >= EE) return;
    int r = ei[e], c = ei[EE + e];
    float nm = -(dis[r] * ew[e] * dis[c]);
    int pidx = offs[c] + atomicAdd(&cursor[c], 1);
    nbrs[pidx] = make_int2(r, __float_as_int(nm));
}

// ---- f32 -> bf16 cast (no transpose) ----
__global__ __launch_bounds__(256) void k_cast(const float* __restrict__ src,
                                              u16* __restrict__ dst, int n) {
    int i = blockIdx.x * 256 + threadIdx.x;
    if (i < n) dst[i] = f2bf(src[i]);
}

// ---- f32 [K][256] -> bf16 [256][K] transpose-cast (weights) ----
__global__ __launch_bounds__(256) void k_cast_T(const float* __restrict__ src,
                                                u16* __restrict__ dst, int K) {
    __shared__ u16 tile[32][33];
    int kt = blockIdx.x * 32, nt = blockIdx.y * 32;
    int tx = threadIdx.x & 31, ty = threadIdx.x >> 5;  // 32 x 8
#pragma unroll
    for (int i = 0; i < 32; i += 8)
        tile[ty + i][tx] = f2bf(src[(size_t)(kt + ty + i) * 256 + (nt + tx)]);
    __syncthreads();
#pragma unroll
    for (int i = 0; i < 32; i += 8)
        dst[(size_t)(nt + ty + i) * K + (kt + tx)] = tile[tx][ty + i];
}

// ---- fold BN affine: s = gamma*rsqrt(var+eps), t = beta - mean*s ----
__global__ __launch_bounds__(256) void k_foldbn(const float* __restrict__ g,
                                                const float* __restrict__ be,
                                                const float* __restrict__ mn,
                                                const float* __restrict__ vr,
                                                float* __restrict__ sc,
                                                float* __restrict__ sh) {
    int t = threadIdx.x;
    if (t < 256) {
        float s = g[t] * rsqrtf(vr[t] + 1e-5f);
        sc[t] = s;
        sh[t] = be[t] - mn[t] * s;
    }
}

// ---- CSR SpMM: one WAVE per node, no LDS, no barriers, 8 gathers in flight ----
// R8-proven form: one row per gather instruction, 8 independent loads in
// flight per wave (MLP hides latency; paired 16B variant was 2x slower).
__global__ __launch_bounds__(256) void k_prop(const u16* __restrict__ x, int ldx,
                                              const u16* __restrict__ xsub, int ldsub,
                                              int dotx2,
                                              u16* __restrict__ out, int ldo,
                                              const int* __restrict__ offs,
                                              const int2* __restrict__ nbrs) {
    int c = __builtin_amdgcn_readfirstlane(blockIdx.x * 4 + (threadIdx.x >> 6));
    int lane = threadIdx.x & 63;
    int s = offs[c], e = offs[c + 1];
    float a0 = 0.f, a1 = 0.f, a2 = 0.f, a3 = 0.f;
    for (int i = s; i < e; i += 8) {
        int2 mm[8];
        ushort4 xv[8];
#pragma unroll
        for (int j = 0; j < 8; j++) mm[j] = nbrs[i + j];
#pragma unroll
        for (int j = 0; j < 8; j++)
            xv[j] = *(const ushort4*)(x + (size_t)mm[j].x * ldx + lane * 4);
#pragma unroll
        for (int j = 0; j < 8; j++) {
            float w = (i + j < e) ? __int_as_float(mm[j].y) : 0.f;
            a0 += w * bf2f(xv[j].x);
            a1 += w * bf2f(xv[j].y);
            a2 += w * bf2f(xv[j].z);
            a3 += w * bf2f(xv[j].w);
        }
    }
    if (dotx2) {
        ushort4 xs = *(const ushort4*)(xsub + (size_t)c * ldsub + lane * 4);
        a0 = 2.f * a0 - bf2f(xs.x);
        a1 = 2.f * a1 - bf2f(xs.y);
        a2 = 2.f * a2 - bf2f(xs.z);
        a3 = 2.f * a3 - bf2f(xs.w);
    }
    ushort4 o;
    o.x = f2bf(a0); o.y = f2bf(a1); o.z = f2bf(a2); o.w = f2bf(a3);
    *(ushort4*)(out + (size_t)c * ldo + lane * 4) = o;
}

// ---- bf16 MFMA GEMM: barrier-DMA, tile M=64 x N=256 (B amortized 2x). ----
// 256 thr / 4 waves; wave wv owns cols wv*64..+63 over all 64 rows (acc 4x4).
// BK=32 -> 24/32 steps; per wave per step: 5 gll16 (4 B + 1 A frag), 8
// ds_read_b128, 16 MFMA (m97 ratio). Staged bytes: B 120 MB + A 30 MB
// (vs 300 MB at M=32) -- duration empirically tracks staged bytes (R8 vs R11).
// Grid 313; last block clamps A rows (per-lane src ok; LDS dest lane*16) and
// guards stores. mode 0: relu -> bf16 via per-wave LDS transpose.
// mode 1: +bias, relu, BN affine, @w2 + b2 -> LDS cross-wave reduce, plain
// store (no atomics, no out memset).
__global__ __launch_bounds__(256, 2) void k_gemm(
    const u16* __restrict__ A0, const u16* __restrict__ A1,
    const u16* __restrict__ A2, const u16* __restrict__ A3,
    int lda0, int lda1, int lda2, int lda3,
    int K, const u16* __restrict__ Bt,
    int mode,
    u16* __restrict__ outb, int ldob,
    const float* __restrict__ bias, const float* __restrict__ sc,
    const float* __restrict__ sh,
    const float* __restrict__ w2, const float* __restrict__ b2,
    float* __restrict__ outlog) {
    __shared__ __align__(16) u16 lds[2 * 20 * 512];  // 40 KB: 2 bufs x 20 frags
    int t = threadIdx.x;
    int wv = t >> 6, l = t & 63;
    int q = l >> 4, l16 = l & 15;
    int m0 = blockIdx.x * 64;
    int n0 = wv * 64;
    const int steps = K >> 5;  // 24 or 32

    f32x4 acc[4][4] = {};  // [mh][nt]

    int arow = min(m0 + wv * 16 + l16, NN - 1);  // wave wv stages A frag mh=wv

    auto stage = [&](int buf, int s) {
        int kt = s * 32;
        u16* base = lds + buf * 20 * 512;
#pragma unroll
        for (int j = 0; j < 4; j++) {
            const u16* bg = Bt + (size_t)((wv * 4 + j) * 16 + l16) * K + kt + q * 8;
            gll16(bg, base + (wv * 4 + j) * 512);
        }
        int ch = kt >> 8;  // wave-uniform -> SGPR select
        const u16* ap;
        int la;
        if (ch == 0) { ap = A0; la = lda0; }
        else if (ch == 1) { ap = A1; la = lda1; }
        else if (ch == 2) { ap = A2; la = lda2; }
        else { ap = A3; la = lda3; }
        gll16(ap + (size_t)arow * la + (kt & 255) + q * 8, base + (16 + wv) * 512);
    };

    stage(0, 0);
    for (int s = 0; s < steps; s++) {
        __syncthreads();  // drains stage(s) DMAs (vmcnt(0)) + prev reads
        if (s + 1 < steps) stage((s + 1) & 1, s + 1);
        const u16* base = lds + (s & 1) * 20 * 512;
        bf16x8 a[4], b[4];
#pragma unroll
        for (int mh = 0; mh < 4; mh++)
            a[mh] = *(const bf16x8*)(base + (16 + mh) * 512 + l * 8);
#pragma unroll
        for (int j = 0; j < 4; j++)
            b[j] = *(const bf16x8*)(base + (wv * 4 + j) * 512 + l * 8);
#pragma unroll
        for (int mh = 0; mh < 4; mh++)
#pragma unroll
            for (int j = 0; j < 4; j++)
                acc[mh][j] =
                    __builtin_amdgcn_mfma_f32_16x16x32_bf16(a[mh], b[j], acc[mh][j], 0, 0, 0);
    }
    __syncthreads();  // all waves done reading K-loop LDS; reuse below

    if (mode == 0) {
        u16* Cs = lds + wv * 4608;  // per-wave [64][72] (9216 B x4 = 36 KB)
#pragma unroll
        for (int mh = 0; mh < 4; mh++)
#pragma unroll
            for (int j = 0; j < 4; j++)
#pragma unroll
                for (int i = 0; i < 4; i++) {
                    float v = acc[mh][j][i];
                    v = v > 0.f ? v : 0.f;
                    Cs[(mh * 16 + q * 4 + i) * 72 + j * 16 + l16] = f2bf(v);
                }
        // same-wave ds_write->ds_read ordered via lgkmcnt
#pragma unroll
        for (int j = 0; j < 8; j++) {
            int f = j * 64 + l;
            int r = f >> 3, cc = (f & 7) * 8;
            uint4 cv = *(const uint4*)&Cs[r * 72 + cc];
            int row = m0 + r;
            if (row < NN) *(uint4*)(outb + (size_t)row * ldob + n0 + cc) = cv;
        }
    } else {
        float bi[4], s4[4], h4[4], wa[4], wb[4];
#pragma unroll
        for (int j = 0; j < 4; j++) {
            int col = n0 + j * 16 + l16;
            bi[j] = bias[col];
            s4[j] = sc[col];
            h4[j] = sh[col];
            wa[j] = w2[2 * col];
            wb[j] = w2[2 * col + 1];
        }
        float* red = (float*)lds;  // [4 waves][64 rows][2]
#pragma unroll
        for (int mh = 0; mh < 4; mh++)
#pragma unroll
            for (int i = 0; i < 4; i++) {
                float p0 = 0.f, p1 = 0.f;
#pragma unroll
                for (int j = 0; j < 4; j++) {
                    float v = acc[mh][j][i] + bi[j];
                    v = v > 0.f ? v : 0.f;
                    v = v * s4[j] + h4[j];
                    p0 += v * wa[j];
                    p1 += v * wb[j];
                }
#pragma unroll
                for (int off = 1; off < 16; off <<= 1) {
                    p0 += __shfl_xor(p0, off, 64);
                    p1 += __shfl_xor(p1, off, 64);
                }
                if (l16 == 0) {
                    int rl = mh * 16 + q * 4 + i;
                    red[(wv * 64 + rl) * 2 + 0] = p0;
                    red[(wv * 64 + rl) * 2 + 1] = p1;
                }
            }
        __syncthreads();
        if (t < 128) {
            int rl = t >> 1, cp = t & 1;
            float v = red[(0 * 64 + rl) * 2 + cp] + red[(1 * 64 + rl) * 2 + cp] +
                      red[(2 * 64 + rl) * 2 + cp] + red[(3 * 64 + rl) * 2 + cp];
            int row = m0 + rl;
            if (row < NN) outlog[(size_t)row * 2 + cp] = v + b2[cp];
        }
    }
}

extern "C" void kernel_launch(void* const* d_in, const int* in_sizes, int n_in,
                              void* d_out, int out_size, void* d_ws, size_t ws_size,
                              hipStream_t stream) {
    const float* features = (const float*)d_in[0];
    const int* ei = (const int*)d_in[1];
    // d_in[2] = edgenet_input (bypassed by edge_weight_override)
    const float* ew = (const float*)d_in[3];
    const float* cheb_w = (const float*)d_in[4];
    const float* w1 = (const float*)d_in[5];
    const float* b1 = (const float*)d_in[6];
    const float* g = (const float*)d_in[7];
    const float* be = (const float*)d_in[8];
    const float* mn = (const float*)d_in[9];
    const float* vr = (const float*)d_in[10];
    const float* w2 = (const float*)d_in[11];
    const float* b2 = (const float*)d_in[12];
    float* out = (float*)d_out;  // [NN*2] logits, then [EE] ew

    char* p = (char*)d_ws;
    auto alloc = [&](size_t bytes) -> char* {
        char* r = p;
        p += (bytes + 255) & ~(size_t)255;
        return r;
    };
    float* deg = (float*)alloc((size_t)NN * 4);
    int* counts = (int*)alloc((size_t)(NN + 1) * 4);
    int* cursor = (int*)alloc((size_t)NN * 4);
    size_t zero_bytes = (size_t)(p - (char*)deg);
    int* offs = (int*)alloc((size_t)(NN + 1) * 4);
    int2* nbrs = (int2*)alloc((size_t)(EE + 8) * 8);
    u16* xb = (u16*)alloc((size_t)NN * 256 * 2);
    u16* tx1 = (u16*)alloc((size_t)NN * 256 * 2);
    u16* tx2 = (u16*)alloc((size_t)NN * 256 * 2);
    u16* jk = (u16*)alloc((size_t)NN * 1024 * 2);
    u16* chebT = (u16*)alloc((size_t)LGN * 3 * 256 * 256 * 2);  // per layer [256][768]
    u16* w1T = (u16*)alloc((size_t)1024 * 256 * 2);             // [256][1024]
    float* sc = (float*)alloc(256 * 4);
    float* sh = (float*)alloc(256 * 4);

    hipMemsetAsync(deg, 0, zero_bytes, stream);
    hipMemsetAsync(nbrs + EE, 0, 8 * sizeof(int2), stream);  // safe overrun pad
    k_edge1<<<(EE + 255) / 256, 256, 0, stream>>>(ei, ew, deg, counts, out + (size_t)NN * 2);
    k_rsqrt<<<(NN + 255) / 256, 256, 0, stream>>>(deg);
    k_scan<<<1, 1024, 0, stream>>>(counts, offs);
    k_scatter<<<(EE + 255) / 256, 256, 0, stream>>>(ei, ew, deg, offs, cursor, nbrs);
    k_cast<<<((NN * 256) + 255) / 256, 256, 0, stream>>>(features, xb, NN * 256);
    for (int i = 0; i < LGN; i++)
        k_cast_T<<<dim3(24, 8), 256, 0, stream>>>(cheb_w + (size_t)i * 768 * 256,
                                                  chebT + (size_t)i * 256 * 768, 768);
    k_cast_T<<<dim3(32, 8), 256, 0, stream>>>(w1, w1T, 1024);
    k_foldbn<<<1, 256, 0, stream>>>(g, be, mn, vr, sc, sh);

    const int gg = (NN + 63) / 64;  // 313 blocks (tile M=64 x N=256)
    for (int i = 0; i < LGN; i++) {
        const u16* x = (i == 0) ? xb : (jk + (size_t)(i - 1) * 256);
        int ldx = (i == 0) ? 256 : 1024;
        k_prop<<<NN / 4, 256, 0, stream>>>(x, ldx, (const u16*)nullptr, 0, 0, tx1, 256, offs,
                                           nbrs);
        k_prop<<<NN / 4, 256, 0, stream>>>(tx1, 256, x, ldx, 1, tx2, 256, offs, nbrs);
        k_gemm<<<gg, 256, 0, stream>>>(
            x, tx1, tx2, (const u16*)nullptr, ldx, 256, 256, 0, 768,
            chebT + (size_t)i * 256 * 768, 0, jk + (size_t)i * 256, 1024, (const float*)nullptr,
            (const float*)nullptr, (const float*)nullptr, (const float*)nullptr,
            (const float*)nullptr, (float*)nullptr);
    }
    k_gemm<<<gg, 256, 0, stream>>>(jk, jk + 256, jk + 512, jk + 768, 1024, 1024, 1024, 1024,
                                   1024, w1T, 1, (u16*)nullptr, 0, b1, sc, sh, w2, b2, out);
}